// Round 4
// baseline (296.817 us; speedup 1.0000x reference)
//
#include <hip/hip_runtime.h>
#include <hip/hip_bf16.h>
#include <stdint.h>

typedef __attribute__((ext_vector_type(8))) short bf16x8;
typedef __attribute__((ext_vector_type(4))) float f32x4;
typedef __attribute__((ext_vector_type(4))) unsigned short u16x4;

#define B_ 4
#define T_ 2048
#define C_ 1024
#define H_ 16
#define D_ 64

// round-to-nearest-even fp32 -> bf16
__device__ __forceinline__ unsigned short f2bf(float f) {
  union { float f; uint32_t u; } v; v.f = f;
  uint32_t u = v.u;
  uint32_t r = (u + 0x7FFFu + ((u >> 16) & 1u)) >> 16;
  return (unsigned short)r;
}

// async global->LDS, 16B per lane; lds dst = wave-uniform base + lane*16 [m97/m104]
__device__ __forceinline__ void gload_lds16(const unsigned short* g, short* l) {
  __builtin_amdgcn_global_load_lds((__attribute__((address_space(1))) void*)(uintptr_t)g,
                                   (__attribute__((address_space(3))) void*)l, 16, 0, 0);
}

// all three fp32->bf16 casts in one kernel
__global__ void __launch_bounds__(256) cast3_f32_bf16(const float* __restrict__ x,
                                                      const float* __restrict__ wq,
                                                      const float* __restrict__ wo,
                                                      unsigned short* __restrict__ xb,
                                                      unsigned short* __restrict__ wqb,
                                                      unsigned short* __restrict__ wob) {
  int i = blockIdx.x * 256 + threadIdx.x;
  const float* s; unsigned short* d; int off;
  if (i < 2097152) { s = x; d = xb; off = i; }
  else if (i < 2097152 + 786432) { s = wq; d = wqb; off = i - 2097152; }
  else { s = wo; d = wob; off = i - 2883584; }
  float4 f = ((const float4*)s)[off];
  u16x4 o;
  o[0] = f2bf(f.x); o[1] = f2bf(f.y); o[2] = f2bf(f.z); o[3] = f2bf(f.w);
  ((u16x4*)d)[off] = o;
}

// qkv = x[8192,1024] @ w_qkv[3072,1024]^T. m97 structure (128x128 tile, BK=32,
// 4 waves 2x2, global_load_lds width=16, unpadded LDS stride 32).
// Epilogue: blocks 0..15 scatter Q/K to [B,H,T,D] (2B stores, 32B granules);
// blocks 16..23 are V-only and store TRANSPOSED [B,H,D,T] via per-wave LDS
// bounce (coalesced 16B stores) — replaces the separate transpose kernel.
__global__ void __launch_bounds__(256) gemm_qkv(const unsigned short* __restrict__ A,
                                                const unsigned short* __restrict__ Bm,
                                                unsigned short* __restrict__ qb,
                                                unsigned short* __restrict__ kb,
                                                unsigned short* __restrict__ vtb) {
  __shared__ short As[128 * 32];
  __shared__ short Bs[128 * 32];
  const int tid = threadIdx.x;
  const int bm = blockIdx.y * 128;
  const int bn = blockIdx.x * 128;
  const int w = tid >> 6;
  const int l = tid & 63;
  const int wm = w >> 1, wn = w & 1;
  const int lm = l & 15, lq = l >> 4;

  const int srow = w * 16 + (l >> 2);
  const int scol = (l & 3) * 8;
  const unsigned short* gA0 = A + (size_t)(bm + srow) * 1024 + scol;
  const unsigned short* gA1 = gA0 + (size_t)64 * 1024;
  const unsigned short* gB0 = Bm + (size_t)(bn + srow) * 1024 + scol;
  const unsigned short* gB1 = gB0 + (size_t)64 * 1024;
  short* dA0 = As + w * 512;
  short* dA1 = As + 2048 + w * 512;
  short* dB0 = Bs + w * 512;
  short* dB1 = Bs + 2048 + w * 512;

  f32x4 acc[4][4];
#pragma unroll
  for (int i = 0; i < 4; i++)
#pragma unroll
    for (int j = 0; j < 4; j++) acc[i][j] = (f32x4){0.f, 0.f, 0.f, 0.f};

  for (int k0 = 0; k0 < 1024; k0 += 32) {
    __syncthreads();
    gload_lds16(gA0 + k0, dA0);
    gload_lds16(gA1 + k0, dA1);
    gload_lds16(gB0 + k0, dB0);
    gload_lds16(gB1 + k0, dB1);
    __syncthreads();
    bf16x8 af[4], bfr[4];
#pragma unroll
    for (int i = 0; i < 4; i++)
      af[i] = *(const bf16x8*)&As[(wm * 64 + 16 * i + lm) * 32 + 8 * lq];
#pragma unroll
    for (int j = 0; j < 4; j++)
      bfr[j] = *(const bf16x8*)&Bs[(wn * 64 + 16 * j + lm) * 32 + 8 * lq];
#pragma unroll
    for (int i = 0; i < 4; i++)
#pragma unroll
      for (int j = 0; j < 4; j++)
        acc[i][j] = __builtin_amdgcn_mfma_f32_16x16x32_bf16(af[i], bfr[j], acc[i][j], 0, 0, 0);
  }

  // C/D layout: col = lane&15, row = (lane>>4)*4 + reg  [m89/m91]
  if (blockIdx.x < 16) {
    // Q/K scatter, identical to the R1 epilogue
#pragma unroll
    for (int i = 0; i < 4; i++) {
#pragma unroll
      for (int j = 0; j < 4; j++) {
#pragma unroll
        for (int r = 0; r < 4; r++) {
          int m = bm + wm * 64 + 16 * i + 4 * lq + r;
          int n = bn + wn * 64 + 16 * j + lm;
          int which = n >> 10, rem = n & 1023;
          int h = rem >> 6, d = rem & 63;
          int b = m >> 11, t = m & 2047;
          unsigned short* dst = (which == 0) ? qb : kb;
          dst[(((size_t)(b * 16 + h)) * 2048 + t) * 64 + d] = f2bf(acc[i][j][r]);
        }
      }
    }
  } else {
    // V: transpose via per-wave LDS region (reuses As/Bs; tp=20 shorts/row)
    __syncthreads();  // all MFMA LDS reads done before reuse
    short* Lw = (w < 2) ? (As + w * 1280) : (Bs + (w - 2) * 1280);
    const int h = ((bn - 2048) >> 6) + wn;
    const int b = bm >> 11;
    const int tbase = (bm & 2047) + wm * 64;
    unsigned short* vrow = vtb + ((size_t)(b * 16 + h) * 64 + l) * 2048 + tbase;
#pragma unroll
    for (int i = 0; i < 4; i++) {
#pragma unroll
      for (int j = 0; j < 4; j++)
#pragma unroll
        for (int r = 0; r < 4; r++)
          Lw[(16 * j + lm) * 20 + 4 * lq + r] = (short)f2bf(acc[i][j][r]);
      // same-wave LDS RAW; compiler inserts lgkmcnt waits
      const short* rp = &Lw[l * 20];
      uint2 a0 = *(const uint2*)(rp + 0);
      uint2 a1 = *(const uint2*)(rp + 4);
      uint2 a2 = *(const uint2*)(rp + 8);
      uint2 a3 = *(const uint2*)(rp + 12);
      uint4 s0; s0.x = a0.x; s0.y = a0.y; s0.z = a1.x; s0.w = a1.y;
      uint4 s1; s1.x = a2.x; s1.y = a2.y; s1.z = a3.x; s1.w = a3.y;
      unsigned short* dst = vrow + 16 * i;
      *(uint4*)(dst) = s0;
      *(uint4*)(dst + 8) = s1;
    }
  }
}

// out = attn[8192,1024] @ w_out[1024,1024]^T, fp32 store. Same m97 structure.
__global__ void __launch_bounds__(256) gemm_out(const unsigned short* __restrict__ A,
                                                const unsigned short* __restrict__ Bm,
                                                float* __restrict__ fo) {
  __shared__ short As[128 * 32];
  __shared__ short Bs[128 * 32];
  const int tid = threadIdx.x;
  const int bm = blockIdx.y * 128;
  const int bn = blockIdx.x * 128;
  const int w = tid >> 6;
  const int l = tid & 63;
  const int wm = w >> 1, wn = w & 1;
  const int lm = l & 15, lq = l >> 4;

  const int srow = w * 16 + (l >> 2);
  const int scol = (l & 3) * 8;
  const unsigned short* gA0 = A + (size_t)(bm + srow) * 1024 + scol;
  const unsigned short* gA1 = gA0 + (size_t)64 * 1024;
  const unsigned short* gB0 = Bm + (size_t)(bn + srow) * 1024 + scol;
  const unsigned short* gB1 = gB0 + (size_t)64 * 1024;
  short* dA0 = As + w * 512;
  short* dA1 = As + 2048 + w * 512;
  short* dB0 = Bs + w * 512;
  short* dB1 = Bs + 2048 + w * 512;

  f32x4 acc[4][4];
#pragma unroll
  for (int i = 0; i < 4; i++)
#pragma unroll
    for (int j = 0; j < 4; j++) acc[i][j] = (f32x4){0.f, 0.f, 0.f, 0.f};

  for (int k0 = 0; k0 < 1024; k0 += 32) {
    __syncthreads();
    gload_lds16(gA0 + k0, dA0);
    gload_lds16(gA1 + k0, dA1);
    gload_lds16(gB0 + k0, dB0);
    gload_lds16(gB1 + k0, dB1);
    __syncthreads();
    bf16x8 af[4], bfr[4];
#pragma unroll
    for (int i = 0; i < 4; i++)
      af[i] = *(const bf16x8*)&As[(wm * 64 + 16 * i + lm) * 32 + 8 * lq];
#pragma unroll
    for (int j = 0; j < 4; j++)
      bfr[j] = *(const bf16x8*)&Bs[(wn * 64 + 16 * j + lm) * 32 + 8 * lq];
#pragma unroll
    for (int i = 0; i < 4; i++)
#pragma unroll
      for (int j = 0; j < 4; j++)
        acc[i][j] = __builtin_amdgcn_mfma_f32_16x16x32_bf16(af[i], bfr[j], acc[i][j], 0, 0, 0);
  }

#pragma unroll
  for (int i = 0; i < 4; i++)
#pragma unroll
    for (int j = 0; j < 4; j++)
#pragma unroll
      for (int r = 0; r < 4; r++) {
        int m = bm + wm * 64 + 16 * i + 4 * lq + r;
        int n = bn + wn * 64 + 16 * j + lm;
        fo[(size_t)m * 1024 + n] = acc[i][j][r];
      }
}

// Single-pass windowed attention: 5 static end-aligned 32-key chunks,
// all QK first (full ILP), one mask/max/exp/sum pass (scale applied here),
// then PV. Q,K [B,H,T,D]; V transposed [B,H,D,T].
__global__ void __launch_bounds__(256) attn_swa(const unsigned short* __restrict__ Qb,
                                               const unsigned short* __restrict__ Kb,
                                               const unsigned short* __restrict__ Vt,
                                               unsigned short* __restrict__ Ob) {
  __shared__ short P[4][5][16 * 40];
  const int wv = threadIdx.x >> 6;
  const int l = threadIdx.x & 63;
  const int wid = blockIdx.x * 4 + wv;
  const int bh = wid >> 7;
  const int t0 = (wid & 127) << 4;
  const int lm = l & 15, lq = l >> 4;
  const size_t base = (size_t)bh * (T_ * D_);

  bf16x8 aq0 = *(const bf16x8*)(Qb + base + (size_t)(t0 + lm) * 64 + 8 * lq);
  bf16x8 aq1 = *(const bf16x8*)(Qb + base + (size_t)(t0 + lm) * 64 + 32 + 8 * lq);

  const int j0b = t0 - 144;
  const float cs = 0.125f * 1.44269504f;  // scale * log2(e)
  float sv[5][8];

#pragma unroll
  for (int c = 0; c < 5; c++) {
    int j0 = j0b + 32 * c;
#pragma unroll
    for (int hh = 0; hh < 2; hh++) {
      int kr = j0 + 16 * hh + lm; if (kr < 0) kr = 0;
      const unsigned short* kp = Kb + base + (size_t)kr * 64;
      bf16x8 b0 = *(const bf16x8*)(kp + 8 * lq);
      bf16x8 b1 = *(const bf16x8*)(kp + 32 + 8 * lq);
      f32x4 s = (f32x4){0.f, 0.f, 0.f, 0.f};
      s = __builtin_amdgcn_mfma_f32_16x16x32_bf16(aq0, b0, s, 0, 0, 0);
      s = __builtin_amdgcn_mfma_f32_16x16x32_bf16(aq1, b1, s, 0, 0, 0);
#pragma unroll
      for (int r = 0; r < 4; r++) sv[c][hh * 4 + r] = s[r];
    }
  }

  float lsum[4];
#pragma unroll
  for (int r = 0; r < 4; r++) {
    int t = t0 + 4 * lq + r;
    int lo = t - 128; if (lo < 0) lo = 0;
    float m2 = -1e30f;
#pragma unroll
    for (int c = 0; c < 5; c++)
#pragma unroll
      for (int hh = 0; hh < 2; hh++) {
        int j = j0b + 32 * c + 16 * hh + lm;
        float s = (j >= lo && j <= t) ? sv[c][hh * 4 + r] * cs : -1e30f;
        sv[c][hh * 4 + r] = s;
        m2 = fmaxf(m2, s);
      }
#pragma unroll
    for (int off = 1; off < 16; off <<= 1) m2 = fmaxf(m2, __shfl_xor(m2, off));
    float ls = 0.f;
#pragma unroll
    for (int c = 0; c < 5; c++)
#pragma unroll
      for (int hh = 0; hh < 2; hh++) {
        float p = __builtin_amdgcn_exp2f(sv[c][hh * 4 + r] - m2);
        sv[c][hh * 4 + r] = p;
        ls += p;
      }
#pragma unroll
    for (int off = 1; off < 16; off <<= 1) ls += __shfl_xor(ls, off);
    lsum[r] = ls;
  }

#pragma unroll
  for (int c = 0; c < 5; c++)
#pragma unroll
    for (int r = 0; r < 4; r++)
#pragma unroll
      for (int hh = 0; hh < 2; hh++)
        P[wv][c][(4 * lq + r) * 40 + 16 * hh + lm] = (short)f2bf(sv[c][hh * 4 + r]);

  f32x4 Oa[4];
#pragma unroll
  for (int jt = 0; jt < 4; jt++) Oa[jt] = (f32x4){0.f, 0.f, 0.f, 0.f};
#pragma unroll
  for (int c = 0; c < 5; c++) {
    bf16x8 pa = *(const bf16x8*)&P[wv][c][lm * 40 + 8 * lq];
    int tb = j0b + 32 * c + 8 * lq; if (tb < 0) tb = 0;  // clamped keys have P=0
#pragma unroll
    for (int jt = 0; jt < 4; jt++) {
      bf16x8 vf = *(const bf16x8*)(Vt + base + (size_t)(16 * jt + lm) * T_ + tb);
      Oa[jt] = __builtin_amdgcn_mfma_f32_16x16x32_bf16(pa, vf, Oa[jt], 0, 0, 0);
    }
  }

  const int b = bh >> 4, h = bh & 15;
#pragma unroll
  for (int r = 0; r < 4; r++) {
    float inv = 1.0f / lsum[r];
    int t = t0 + 4 * lq + r;
#pragma unroll
    for (int jt = 0; jt < 4; jt++) {
      int cc = h * 64 + 16 * jt + lm;
      Ob[((size_t)(b * T_ + t)) * 1024 + cc] = f2bf(Oa[jt][r] * inv);
    }
  }
}

extern "C" void kernel_launch(void* const* d_in, const int* in_sizes, int n_in,
                              void* d_out, int out_size, void* d_ws, size_t ws_size,
                              hipStream_t stream) {
  const float* x = (const float*)d_in[0];
  const float* w_qkv = (const float*)d_in[1];
  const float* w_out = (const float*)d_in[2];
  float* out = (float*)d_out;

  // ws layout (72 MB): xb dead after gemm_qkv -> reused as attn output ob
  unsigned short* xb = (unsigned short*)d_ws;                // 8192*1024
  unsigned short* wqkvb = xb + (size_t)8192 * 1024;          // 3072*1024
  unsigned short* woutb = wqkvb + (size_t)3072 * 1024;       // 1024*1024
  unsigned short* qb = woutb + (size_t)1024 * 1024;          // 64*2048*64
  unsigned short* kb = qb + (size_t)64 * 2048 * 64;
  unsigned short* vtb = kb + (size_t)64 * 2048 * 64;         // [B,H,D,T]
  unsigned short* ob = xb;

  cast3_f32_bf16<<<12288, 256, 0, stream>>>(x, w_qkv, w_out, xb, wqkvb, woutb);
  gemm_qkv<<<dim3(24, 64), 256, 0, stream>>>(xb, wqkvb, qb, kb, vtb);
  attn_swa<<<2048, 256, 0, stream>>>(qb, kb, vtb, ob);
  gemm_out<<<dim3(8, 64), 256, 0, stream>>>(ob, woutb, out);
}

// Round 5
// 239.019 us; speedup vs baseline: 1.2418x; 1.2418x over previous
//
#include <hip/hip_runtime.h>
#include <hip/hip_bf16.h>
#include <stdint.h>

typedef __attribute__((ext_vector_type(8))) short bf16x8;
typedef __attribute__((ext_vector_type(4))) float f32x4;
typedef __attribute__((ext_vector_type(4))) unsigned short u16x4;

#define B_ 4
#define T_ 2048
#define C_ 1024
#define H_ 16
#define D_ 64

// round-to-nearest-even fp32 -> bf16
__device__ __forceinline__ unsigned short f2bf(float f) {
  union { float f; uint32_t u; } v; v.f = f;
  uint32_t u = v.u;
  uint32_t r = (u + 0x7FFFu + ((u >> 16) & 1u)) >> 16;
  return (unsigned short)r;
}

// async global->LDS, 16B per lane; lds dst = wave-uniform base + lane*16 [m97/m104]
__device__ __forceinline__ void gload_lds16(const unsigned short* g, short* l) {
  __builtin_amdgcn_global_load_lds((__attribute__((address_space(1))) void*)(uintptr_t)g,
                                   (__attribute__((address_space(3))) void*)l, 16, 0, 0);
}

// all three fp32->bf16 casts in one kernel. Q-weight rows (first 1024 rows of
// w_qkv = first 262144 float4) are pre-scaled by softmax scale*log2e, so the
// attention kernel's scores come out pre-scaled for exp2.
__global__ void __launch_bounds__(256) cast3_f32_bf16(const float* __restrict__ x,
                                                      const float* __restrict__ wq,
                                                      const float* __restrict__ wo,
                                                      unsigned short* __restrict__ xb,
                                                      unsigned short* __restrict__ wqb,
                                                      unsigned short* __restrict__ wob) {
  int i = blockIdx.x * 256 + threadIdx.x;
  const float* s; unsigned short* d; int off; float sc = 1.0f;
  if (i < 2097152) { s = x; d = xb; off = i; }
  else if (i < 2097152 + 786432) {
    s = wq; d = wqb; off = i - 2097152;
    if (off < 262144) sc = 0.1803368801f;  // 0.125 * log2(e)
  } else { s = wo; d = wob; off = i - 2883584; }
  float4 f = ((const float4*)s)[off];
  u16x4 o;
  o[0] = f2bf(f.x * sc); o[1] = f2bf(f.y * sc); o[2] = f2bf(f.z * sc); o[3] = f2bf(f.w * sc);
  ((u16x4*)d)[off] = o;
}

// qkv = x[8192,1024] @ w_qkv[3072,1024]^T. m97 structure: 128x128 tile, BK=32,
// 4 waves 2x2, global_load_lds width=16, unpadded LDS stride 32.
// Simple scatter epilogue (keep VGPRs low — R4's fused-transpose epilogue cost
// 132 VGPR -> 11% occupancy -> 2x slowdown of the whole K-loop).
__global__ void __launch_bounds__(256) gemm_qkv(const unsigned short* __restrict__ A,
                                                const unsigned short* __restrict__ Bm,
                                                unsigned short* __restrict__ qb,
                                                unsigned short* __restrict__ kb,
                                                unsigned short* __restrict__ vb) {
  __shared__ short As[128 * 32];
  __shared__ short Bs[128 * 32];
  const int tid = threadIdx.x;
  const int bm = blockIdx.y * 128;
  const int bn = blockIdx.x * 128;
  const int w = tid >> 6;
  const int l = tid & 63;
  const int wm = w >> 1, wn = w & 1;
  const int lm = l & 15, lq = l >> 4;

  const int srow = w * 16 + (l >> 2);
  const int scol = (l & 3) * 8;
  const unsigned short* gA0 = A + (size_t)(bm + srow) * 1024 + scol;
  const unsigned short* gA1 = gA0 + (size_t)64 * 1024;
  const unsigned short* gB0 = Bm + (size_t)(bn + srow) * 1024 + scol;
  const unsigned short* gB1 = gB0 + (size_t)64 * 1024;
  short* dA0 = As + w * 512;
  short* dA1 = As + 2048 + w * 512;
  short* dB0 = Bs + w * 512;
  short* dB1 = Bs + 2048 + w * 512;

  f32x4 acc[4][4];
#pragma unroll
  for (int i = 0; i < 4; i++)
#pragma unroll
    for (int j = 0; j < 4; j++) acc[i][j] = (f32x4){0.f, 0.f, 0.f, 0.f};

  for (int k0 = 0; k0 < 1024; k0 += 32) {
    __syncthreads();
    gload_lds16(gA0 + k0, dA0);
    gload_lds16(gA1 + k0, dA1);
    gload_lds16(gB0 + k0, dB0);
    gload_lds16(gB1 + k0, dB1);
    __syncthreads();
    bf16x8 af[4], bfr[4];
#pragma unroll
    for (int i = 0; i < 4; i++)
      af[i] = *(const bf16x8*)&As[(wm * 64 + 16 * i + lm) * 32 + 8 * lq];
#pragma unroll
    for (int j = 0; j < 4; j++)
      bfr[j] = *(const bf16x8*)&Bs[(wn * 64 + 16 * j + lm) * 32 + 8 * lq];
#pragma unroll
    for (int i = 0; i < 4; i++)
#pragma unroll
      for (int j = 0; j < 4; j++)
        acc[i][j] = __builtin_amdgcn_mfma_f32_16x16x32_bf16(af[i], bfr[j], acc[i][j], 0, 0, 0);
  }

  // C/D layout: col = lane&15, row = (lane>>4)*4 + reg  [m89/m91]
#pragma unroll
  for (int i = 0; i < 4; i++) {
#pragma unroll
    for (int j = 0; j < 4; j++) {
#pragma unroll
      for (int r = 0; r < 4; r++) {
        int m = bm + wm * 64 + 16 * i + 4 * lq + r;
        int n = bn + wn * 64 + 16 * j + lm;
        int which = n >> 10, rem = n & 1023;
        int h = rem >> 6, d = rem & 63;
        int b = m >> 11, t = m & 2047;
        unsigned short* dst = (which == 0) ? qb : ((which == 1) ? kb : vb);
        dst[(((size_t)(b * 16 + h)) * 2048 + t) * 64 + d] = f2bf(acc[i][j][r]);
      }
    }
  }
}

// out = attn[8192,1024] @ w_out[1024,1024]^T, fp32 store. Same m97 structure.
__global__ void __launch_bounds__(256) gemm_out(const unsigned short* __restrict__ A,
                                                const unsigned short* __restrict__ Bm,
                                                float* __restrict__ fo) {
  __shared__ short As[128 * 32];
  __shared__ short Bs[128 * 32];
  const int tid = threadIdx.x;
  const int bm = blockIdx.y * 128;
  const int bn = blockIdx.x * 128;
  const int w = tid >> 6;
  const int l = tid & 63;
  const int wm = w >> 1, wn = w & 1;
  const int lm = l & 15, lq = l >> 4;

  const int srow = w * 16 + (l >> 2);
  const int scol = (l & 3) * 8;
  const unsigned short* gA0 = A + (size_t)(bm + srow) * 1024 + scol;
  const unsigned short* gA1 = gA0 + (size_t)64 * 1024;
  const unsigned short* gB0 = Bm + (size_t)(bn + srow) * 1024 + scol;
  const unsigned short* gB1 = gB0 + (size_t)64 * 1024;
  short* dA0 = As + w * 512;
  short* dA1 = As + 2048 + w * 512;
  short* dB0 = Bs + w * 512;
  short* dB1 = Bs + 2048 + w * 512;

  f32x4 acc[4][4];
#pragma unroll
  for (int i = 0; i < 4; i++)
#pragma unroll
    for (int j = 0; j < 4; j++) acc[i][j] = (f32x4){0.f, 0.f, 0.f, 0.f};

  for (int k0 = 0; k0 < 1024; k0 += 32) {
    __syncthreads();
    gload_lds16(gA0 + k0, dA0);
    gload_lds16(gA1 + k0, dA1);
    gload_lds16(gB0 + k0, dB0);
    gload_lds16(gB1 + k0, dB1);
    __syncthreads();
    bf16x8 af[4], bfr[4];
#pragma unroll
    for (int i = 0; i < 4; i++)
      af[i] = *(const bf16x8*)&As[(wm * 64 + 16 * i + lm) * 32 + 8 * lq];
#pragma unroll
    for (int j = 0; j < 4; j++)
      bfr[j] = *(const bf16x8*)&Bs[(wn * 64 + 16 * j + lm) * 32 + 8 * lq];
#pragma unroll
    for (int i = 0; i < 4; i++)
#pragma unroll
      for (int j = 0; j < 4; j++)
        acc[i][j] = __builtin_amdgcn_mfma_f32_16x16x32_bf16(af[i], bfr[j], acc[i][j], 0, 0, 0);
  }

#pragma unroll
  for (int i = 0; i < 4; i++)
#pragma unroll
    for (int j = 0; j < 4; j++)
#pragma unroll
      for (int r = 0; r < 4; r++) {
        int m = bm + wm * 64 + 16 * i + 4 * lq + r;
        int n = bn + wn * 64 + 16 * j + lm;
        fo[(size_t)m * 1024 + n] = acc[i][j][r];
      }
}

// V [B,H,T,D] -> Vt [B,H,D,T]
__global__ void __launch_bounds__(256) transpose_v(const unsigned short* __restrict__ Vb,
                                                   unsigned short* __restrict__ Vt) {
  __shared__ unsigned short Ls[64 * 66];
  const int tid = threadIdx.x;
  const int bh = blockIdx.y;
  const int t0 = blockIdx.x * 64;
  const size_t base = (size_t)bh * (T_ * D_);
  const int d0 = (tid & 7) * 8;
  const int it = tid >> 3;
#pragma unroll
  for (int p = 0; p < 2; p++) {
    int t = it + 32 * p;
    bf16x8 v = *(const bf16x8*)(Vb + base + (size_t)(t0 + t) * 64 + d0);
#pragma unroll
    for (int e = 0; e < 8; e++) Ls[(d0 + e) * 66 + t] = (unsigned short)v[e];
  }
  __syncthreads();
  const int d = tid >> 2;
  const int c = tid & 3;
  uint32_t r[8];
  const uint32_t* Lw = (const uint32_t*)&Ls[d * 66 + c * 16];
#pragma unroll
  for (int wj = 0; wj < 8; wj++) r[wj] = Lw[wj];
  unsigned short* o = Vt + base + (size_t)d * T_ + t0 + c * 16;
  *(uint4*)o = *(const uint4*)&r[0];
  *(uint4*)(o + 8) = *(const uint4*)&r[4];
}

// Single-pass windowed attention: 5 static end-aligned 32-key chunks, all QK
// first (full ILP), one mask/max/exp2/sum pass, then PV. Q pre-scaled via
// w_qkv cast. Q,K [B,H,T,D]; V transposed [B,H,D,T].
__global__ void __launch_bounds__(256) attn_swa(const unsigned short* __restrict__ Qb,
                                               const unsigned short* __restrict__ Kb,
                                               const unsigned short* __restrict__ Vt,
                                               unsigned short* __restrict__ Ob) {
  __shared__ short P[4][5][16 * 40];
  const int wv = threadIdx.x >> 6;
  const int l = threadIdx.x & 63;
  const int wid = blockIdx.x * 4 + wv;
  const int bh = wid >> 7;
  const int t0 = (wid & 127) << 4;
  const int lm = l & 15, lq = l >> 4;
  const size_t base = (size_t)bh * (T_ * D_);

  bf16x8 aq0 = *(const bf16x8*)(Qb + base + (size_t)(t0 + lm) * 64 + 8 * lq);
  bf16x8 aq1 = *(const bf16x8*)(Qb + base + (size_t)(t0 + lm) * 64 + 32 + 8 * lq);

  const int j0b = t0 - 144;
  float sv[5][8];

#pragma unroll
  for (int c = 0; c < 5; c++) {
    int j0 = j0b + 32 * c;
#pragma unroll
    for (int hh = 0; hh < 2; hh++) {
      int kr = j0 + 16 * hh + lm; if (kr < 0) kr = 0;
      const unsigned short* kp = Kb + base + (size_t)kr * 64;
      bf16x8 b0 = *(const bf16x8*)(kp + 8 * lq);
      bf16x8 b1 = *(const bf16x8*)(kp + 32 + 8 * lq);
      f32x4 s = (f32x4){0.f, 0.f, 0.f, 0.f};
      s = __builtin_amdgcn_mfma_f32_16x16x32_bf16(aq0, b0, s, 0, 0, 0);
      s = __builtin_amdgcn_mfma_f32_16x16x32_bf16(aq1, b1, s, 0, 0, 0);
#pragma unroll
      for (int r = 0; r < 4; r++) sv[c][hh * 4 + r] = s[r];
    }
  }

  float lsum[4];
#pragma unroll
  for (int r = 0; r < 4; r++) {
    int t = t0 + 4 * lq + r;
    int lo = t - 128; if (lo < 0) lo = 0;
    float m2 = -1e30f;
#pragma unroll
    for (int c = 0; c < 5; c++)
#pragma unroll
      for (int hh = 0; hh < 2; hh++) {
        int j = j0b + 32 * c + 16 * hh + lm;
        float s = (j >= lo && j <= t) ? sv[c][hh * 4 + r] : -1e30f;
        sv[c][hh * 4 + r] = s;
        m2 = fmaxf(m2, s);
      }
#pragma unroll
    for (int off = 1; off < 16; off <<= 1) m2 = fmaxf(m2, __shfl_xor(m2, off));
    float ls = 0.f;
#pragma unroll
    for (int c = 0; c < 5; c++)
#pragma unroll
      for (int hh = 0; hh < 2; hh++) {
        float p = __builtin_amdgcn_exp2f(sv[c][hh * 4 + r] - m2);
        sv[c][hh * 4 + r] = p;
        ls += p;
      }
#pragma unroll
    for (int off = 1; off < 16; off <<= 1) ls += __shfl_xor(ls, off);
    lsum[r] = ls;
  }

#pragma unroll
  for (int c = 0; c < 5; c++)
#pragma unroll
    for (int r = 0; r < 4; r++)
#pragma unroll
      for (int hh = 0; hh < 2; hh++)
        P[wv][c][(4 * lq + r) * 40 + 16 * hh + lm] = (short)f2bf(sv[c][hh * 4 + r]);

  f32x4 Oa[4];
#pragma unroll
  for (int jt = 0; jt < 4; jt++) Oa[jt] = (f32x4){0.f, 0.f, 0.f, 0.f};
#pragma unroll
  for (int c = 0; c < 5; c++) {
    bf16x8 pa = *(const bf16x8*)&P[wv][c][lm * 40 + 8 * lq];
    int tb = j0b + 32 * c + 8 * lq; if (tb < 0) tb = 0;  // clamped keys have P=0
#pragma unroll
    for (int jt = 0; jt < 4; jt++) {
      bf16x8 vf = *(const bf16x8*)(Vt + base + (size_t)(16 * jt + lm) * T_ + tb);
      Oa[jt] = __builtin_amdgcn_mfma_f32_16x16x32_bf16(pa, vf, Oa[jt], 0, 0, 0);
    }
  }

  const int b = bh >> 4, h = bh & 15;
#pragma unroll
  for (int r = 0; r < 4; r++) {
    float inv = 1.0f / lsum[r];
    int t = t0 + 4 * lq + r;
#pragma unroll
    for (int jt = 0; jt < 4; jt++) {
      int cc = h * 64 + 16 * jt + lm;
      Ob[((size_t)(b * T_ + t)) * 1024 + cc] = f2bf(Oa[jt][r] * inv);
    }
  }
}

extern "C" void kernel_launch(void* const* d_in, const int* in_sizes, int n_in,
                              void* d_out, int out_size, void* d_ws, size_t ws_size,
                              hipStream_t stream) {
  const float* x = (const float*)d_in[0];
  const float* w_qkv = (const float*)d_in[1];
  const float* w_out = (const float*)d_in[2];
  float* out = (float*)d_out;

  // ws layout (~75.5 MB), aliasing: xb dead after gemm_qkv -> vtb;
  // vb dead after transpose_v -> ob
  unsigned short* xb = (unsigned short*)d_ws;                // 8192*1024
  unsigned short* wqkvb = xb + (size_t)8192 * 1024;          // 3072*1024
  unsigned short* woutb = wqkvb + (size_t)3072 * 1024;       // 1024*1024
  unsigned short* qb = woutb + (size_t)1024 * 1024;          // 64*2048*64
  unsigned short* kb = qb + (size_t)64 * 2048 * 64;
  unsigned short* vb = kb + (size_t)64 * 2048 * 64;
  unsigned short* vtb = xb;
  unsigned short* ob = vb;

  cast3_f32_bf16<<<12288, 256, 0, stream>>>(x, w_qkv, w_out, xb, wqkvb, woutb);
  gemm_qkv<<<dim3(24, 64), 256, 0, stream>>>(xb, wqkvb, qb, kb, vb);
  transpose_v<<<dim3(32, 64), 256, 0, stream>>>(vb, vtb);
  attn_swa<<<2048, 256, 0, stream>>>(qb, kb, vtb, ob);
  gemm_out<<<dim3(8, 64), 256, 0, stream>>>(ob, woutb, out);
}

// Round 6
// 234.807 us; speedup vs baseline: 1.2641x; 1.0179x over previous
//
#include <hip/hip_runtime.h>
#include <hip/hip_bf16.h>
#include <stdint.h>

typedef __attribute__((ext_vector_type(8))) short bf16x8;
typedef __attribute__((ext_vector_type(4))) float f32x4;
typedef __attribute__((ext_vector_type(4))) unsigned short u16x4;

#define B_ 4
#define T_ 2048
#define C_ 1024
#define H_ 16
#define D_ 64

// round-to-nearest-even fp32 -> bf16
__device__ __forceinline__ unsigned short f2bf(float f) {
  union { float f; uint32_t u; } v; v.f = f;
  uint32_t u = v.u;
  uint32_t r = (u + 0x7FFFu + ((u >> 16) & 1u)) >> 16;
  return (unsigned short)r;
}

// async global->LDS, 16B per lane; lds dst = wave-uniform base + lane*16 [m97/m104]
__device__ __forceinline__ void gload_lds16(const unsigned short* g, short* l) {
  __builtin_amdgcn_global_load_lds((__attribute__((address_space(1))) void*)(uintptr_t)g,
                                   (__attribute__((address_space(3))) void*)l, 16, 0, 0);
}

// all three fp32->bf16 casts in one kernel. Q-weight rows pre-scaled by
// softmax scale*log2e so attention scores come out exp2-ready.
__global__ void __launch_bounds__(256) cast3_f32_bf16(const float* __restrict__ x,
                                                      const float* __restrict__ wq,
                                                      const float* __restrict__ wo,
                                                      unsigned short* __restrict__ xb,
                                                      unsigned short* __restrict__ wqb,
                                                      unsigned short* __restrict__ wob) {
  int i = blockIdx.x * 256 + threadIdx.x;
  const float* s; unsigned short* d; int off; float sc = 1.0f;
  if (i < 2097152) { s = x; d = xb; off = i; }
  else if (i < 2097152 + 786432) {
    s = wq; d = wqb; off = i - 2097152;
    if (off < 262144) sc = 0.1803368801f;  // 0.125 * log2(e)
  } else { s = wo; d = wob; off = i - 2883584; }
  float4 f = ((const float4*)s)[off];
  u16x4 o;
  o[0] = f2bf(f.x * sc); o[1] = f2bf(f.y * sc); o[2] = f2bf(f.z * sc); o[3] = f2bf(f.w * sc);
  ((u16x4*)d)[off] = o;
}

// qkv = x[8192,1024] @ w_qkv[3072,1024]^T. m97 structure (proven 70 us / 68 VGPR).
__global__ void __launch_bounds__(256) gemm_qkv(const unsigned short* __restrict__ A,
                                                const unsigned short* __restrict__ Bm,
                                                unsigned short* __restrict__ qb,
                                                unsigned short* __restrict__ kb,
                                                unsigned short* __restrict__ vb) {
  __shared__ short As[128 * 32];
  __shared__ short Bs[128 * 32];
  const int tid = threadIdx.x;
  const int bm = blockIdx.y * 128;
  const int bn = blockIdx.x * 128;
  const int w = tid >> 6;
  const int l = tid & 63;
  const int wm = w >> 1, wn = w & 1;
  const int lm = l & 15, lq = l >> 4;

  const int srow = w * 16 + (l >> 2);
  const int scol = (l & 3) * 8;
  const unsigned short* gA0 = A + (size_t)(bm + srow) * 1024 + scol;
  const unsigned short* gA1 = gA0 + (size_t)64 * 1024;
  const unsigned short* gB0 = Bm + (size_t)(bn + srow) * 1024 + scol;
  const unsigned short* gB1 = gB0 + (size_t)64 * 1024;
  short* dA0 = As + w * 512;
  short* dA1 = As + 2048 + w * 512;
  short* dB0 = Bs + w * 512;
  short* dB1 = Bs + 2048 + w * 512;

  f32x4 acc[4][4];
#pragma unroll
  for (int i = 0; i < 4; i++)
#pragma unroll
    for (int j = 0; j < 4; j++) acc[i][j] = (f32x4){0.f, 0.f, 0.f, 0.f};

  for (int k0 = 0; k0 < 1024; k0 += 32) {
    __syncthreads();
    gload_lds16(gA0 + k0, dA0);
    gload_lds16(gA1 + k0, dA1);
    gload_lds16(gB0 + k0, dB0);
    gload_lds16(gB1 + k0, dB1);
    __syncthreads();
    bf16x8 af[4], bfr[4];
#pragma unroll
    for (int i = 0; i < 4; i++)
      af[i] = *(const bf16x8*)&As[(wm * 64 + 16 * i + lm) * 32 + 8 * lq];
#pragma unroll
    for (int j = 0; j < 4; j++)
      bfr[j] = *(const bf16x8*)&Bs[(wn * 64 + 16 * j + lm) * 32 + 8 * lq];
#pragma unroll
    for (int i = 0; i < 4; i++)
#pragma unroll
      for (int j = 0; j < 4; j++)
        acc[i][j] = __builtin_amdgcn_mfma_f32_16x16x32_bf16(af[i], bfr[j], acc[i][j], 0, 0, 0);
  }

  // C/D layout: col = lane&15, row = (lane>>4)*4 + reg  [m89/m91]
#pragma unroll
  for (int i = 0; i < 4; i++) {
#pragma unroll
    for (int j = 0; j < 4; j++) {
#pragma unroll
      for (int r = 0; r < 4; r++) {
        int m = bm + wm * 64 + 16 * i + 4 * lq + r;
        int n = bn + wn * 64 + 16 * j + lm;
        int which = n >> 10, rem = n & 1023;
        int h = rem >> 6, d = rem & 63;
        int b = m >> 11, t = m & 2047;
        unsigned short* dst = (which == 0) ? qb : ((which == 1) ? kb : vb);
        dst[(((size_t)(b * 16 + h)) * 2048 + t) * 64 + d] = f2bf(acc[i][j][r]);
      }
    }
  }
}

// out = attn[8192,1024] @ w_out[1024,1024]^T, fp32 store. Same m97 structure.
__global__ void __launch_bounds__(256) gemm_out(const unsigned short* __restrict__ A,
                                                const unsigned short* __restrict__ Bm,
                                                float* __restrict__ fo) {
  __shared__ short As[128 * 32];
  __shared__ short Bs[128 * 32];
  const int tid = threadIdx.x;
  const int bm = blockIdx.y * 128;
  const int bn = blockIdx.x * 128;
  const int w = tid >> 6;
  const int l = tid & 63;
  const int wm = w >> 1, wn = w & 1;
  const int lm = l & 15, lq = l >> 4;

  const int srow = w * 16 + (l >> 2);
  const int scol = (l & 3) * 8;
  const unsigned short* gA0 = A + (size_t)(bm + srow) * 1024 + scol;
  const unsigned short* gA1 = gA0 + (size_t)64 * 1024;
  const unsigned short* gB0 = Bm + (size_t)(bn + srow) * 1024 + scol;
  const unsigned short* gB1 = gB0 + (size_t)64 * 1024;
  short* dA0 = As + w * 512;
  short* dA1 = As + 2048 + w * 512;
  short* dB0 = Bs + w * 512;
  short* dB1 = Bs + 2048 + w * 512;

  f32x4 acc[4][4];
#pragma unroll
  for (int i = 0; i < 4; i++)
#pragma unroll
    for (int j = 0; j < 4; j++) acc[i][j] = (f32x4){0.f, 0.f, 0.f, 0.f};

  for (int k0 = 0; k0 < 1024; k0 += 32) {
    __syncthreads();
    gload_lds16(gA0 + k0, dA0);
    gload_lds16(gA1 + k0, dA1);
    gload_lds16(gB0 + k0, dB0);
    gload_lds16(gB1 + k0, dB1);
    __syncthreads();
    bf16x8 af[4], bfr[4];
#pragma unroll
    for (int i = 0; i < 4; i++)
      af[i] = *(const bf16x8*)&As[(wm * 64 + 16 * i + lm) * 32 + 8 * lq];
#pragma unroll
    for (int j = 0; j < 4; j++)
      bfr[j] = *(const bf16x8*)&Bs[(wn * 64 + 16 * j + lm) * 32 + 8 * lq];
#pragma unroll
    for (int i = 0; i < 4; i++)
#pragma unroll
      for (int j = 0; j < 4; j++)
        acc[i][j] = __builtin_amdgcn_mfma_f32_16x16x32_bf16(af[i], bfr[j], acc[i][j], 0, 0, 0);
  }

#pragma unroll
  for (int i = 0; i < 4; i++)
#pragma unroll
    for (int j = 0; j < 4; j++)
#pragma unroll
      for (int r = 0; r < 4; r++) {
        int m = bm + wm * 64 + 16 * i + 4 * lq + r;
        int n = bn + wn * 64 + 16 * j + lm;
        fo[(size_t)m * 1024 + n] = acc[i][j][r];
      }
}

// V [B,H,T,D] -> Vt [B,H,D,T]
__global__ void __launch_bounds__(256) transpose_v(const unsigned short* __restrict__ Vb,
                                                   unsigned short* __restrict__ Vt) {
  __shared__ unsigned short Ls[64 * 66];
  const int tid = threadIdx.x;
  const int bh = blockIdx.y;
  const int t0 = blockIdx.x * 64;
  const size_t base = (size_t)bh * (T_ * D_);
  const int d0 = (tid & 7) * 8;
  const int it = tid >> 3;
#pragma unroll
  for (int p = 0; p < 2; p++) {
    int t = it + 32 * p;
    bf16x8 v = *(const bf16x8*)(Vb + base + (size_t)(t0 + t) * 64 + d0);
#pragma unroll
    for (int e = 0; e < 8; e++) Ls[(d0 + e) * 66 + t] = (unsigned short)v[e];
  }
  __syncthreads();
  const int d = tid >> 2;
  const int c = tid & 3;
  uint32_t r[8];
  const uint32_t* Lw = (const uint32_t*)&Ls[d * 66 + c * 16];
#pragma unroll
  for (int wj = 0; wj < 8; wj++) r[wj] = Lw[wj];
  unsigned short* o = Vt + base + (size_t)d * T_ + t0 + c * 16;
  *(uint4*)o = *(const uint4*)&r[0];
  *(uint4*)(o + 8) = *(const uint4*)&r[4];
}

// Windowed attention v3. One wave per 16-query tile; 5 end-aligned 32-key
// chunks processed in a NON-unrolled loop (bounded VGPRs — suspect R2-R5
// versions spilled: 20 hoisted K-fragments + S array > 256 VGPR).
// No max-subtraction: Q pre-scaled by scale*log2e, scores |s| ~ O(5),
// exp2 is overflow-safe and softmax is shift-invariant.
// XCD-locality swizzle: each XCD gets 8 whole (b,h) groups in sequential
// t-order, so K/V window re-reads hit that XCD's L2 (768 KB << 4 MB).
__global__ void __launch_bounds__(256) attn_swa(const unsigned short* __restrict__ Qb,
                                               const unsigned short* __restrict__ Kb,
                                               const unsigned short* __restrict__ Vt,
                                               unsigned short* __restrict__ Ob) {
  __shared__ short P[4][16 * 40];  // per-wave, reused each chunk (5 KB/block)
  const int wv = threadIdx.x >> 6;
  const int l = threadIdx.x & 63;
  const int lin = (blockIdx.x & 7) * 256 + (blockIdx.x >> 3);
  const int bh = lin >> 5;
  const int t0 = (lin & 31) * 64 + wv * 16;
  const int lm = l & 15, lq = l >> 4;
  const size_t base = (size_t)bh * (T_ * D_);

  bf16x8 aq0 = *(const bf16x8*)(Qb + base + (size_t)(t0 + lm) * 64 + 8 * lq);
  bf16x8 aq1 = *(const bf16x8*)(Qb + base + (size_t)(t0 + lm) * 64 + 32 + 8 * lq);

  f32x4 Oa[4];
#pragma unroll
  for (int jt = 0; jt < 4; jt++) Oa[jt] = (f32x4){0.f, 0.f, 0.f, 0.f};
  float lp[4] = {0.f, 0.f, 0.f, 0.f};  // per-lane partial row sums

  const int j0b = t0 - 144;
#pragma unroll 1
  for (int c = 0; c < 5; c++) {
    int j0 = j0b + 32 * c;
    float pv[8];
#pragma unroll
    for (int hh = 0; hh < 2; hh++) {
      int kr = j0 + 16 * hh + lm; if (kr < 0) kr = 0;  // clamped rows masked below
      const unsigned short* kp = Kb + base + (size_t)kr * 64;
      bf16x8 b0 = *(const bf16x8*)(kp + 8 * lq);
      bf16x8 b1 = *(const bf16x8*)(kp + 32 + 8 * lq);
      f32x4 s = (f32x4){0.f, 0.f, 0.f, 0.f};
      s = __builtin_amdgcn_mfma_f32_16x16x32_bf16(aq0, b0, s, 0, 0, 0);
      s = __builtin_amdgcn_mfma_f32_16x16x32_bf16(aq1, b1, s, 0, 0, 0);
      int j = j0 + 16 * hh + lm;
#pragma unroll
      for (int r = 0; r < 4; r++) {
        int t = t0 + 4 * lq + r;
        bool ok = (j >= 0) && (j <= t) && (j >= t - 128);
        float p = ok ? __builtin_amdgcn_exp2f(s[r]) : 0.f;
        pv[hh * 4 + r] = p;
        lp[r] += p;
      }
    }
    // C-layout -> LDS -> A-layout (m120); same-wave RAW, no barrier
#pragma unroll
    for (int r = 0; r < 4; r++) {
      P[wv][(4 * lq + r) * 40 + lm] = (short)f2bf(pv[r]);
      P[wv][(4 * lq + r) * 40 + 16 + lm] = (short)f2bf(pv[4 + r]);
    }
    bf16x8 pa = *(const bf16x8*)&P[wv][lm * 40 + 8 * lq];
    int tb = j0 + 8 * lq; if (tb < 0) tb = 0;  // clamped keys have P=0
#pragma unroll
    for (int jt = 0; jt < 4; jt++) {
      bf16x8 vf = *(const bf16x8*)(Vt + base + (size_t)(16 * jt + lm) * T_ + tb);
      Oa[jt] = __builtin_amdgcn_mfma_f32_16x16x32_bf16(pa, vf, Oa[jt], 0, 0, 0);
    }
  }

  const int b = bh >> 4, h = bh & 15;
#pragma unroll
  for (int r = 0; r < 4; r++) {
    float ls = lp[r];
#pragma unroll
    for (int off = 1; off < 16; off <<= 1) ls += __shfl_xor(ls, off);
    float inv = 1.0f / ls;
    int t = t0 + 4 * lq + r;
#pragma unroll
    for (int jt = 0; jt < 4; jt++) {
      int cc = h * 64 + 16 * jt + lm;
      Ob[((size_t)(b * T_ + t)) * 1024 + cc] = f2bf(Oa[jt][r] * inv);
    }
  }
}

extern "C" void kernel_launch(void* const* d_in, const int* in_sizes, int n_in,
                              void* d_out, int out_size, void* d_ws, size_t ws_size,
                              hipStream_t stream) {
  const float* x = (const float*)d_in[0];
  const float* w_qkv = (const float*)d_in[1];
  const float* w_out = (const float*)d_in[2];
  float* out = (float*)d_out;

  // ws layout (~75.5 MB), aliasing: xb dead after gemm_qkv -> vtb;
  // vb dead after transpose_v -> ob
  unsigned short* xb = (unsigned short*)d_ws;                // 8192*1024
  unsigned short* wqkvb = xb + (size_t)8192 * 1024;          // 3072*1024
  unsigned short* woutb = wqkvb + (size_t)3072 * 1024;       // 1024*1024
  unsigned short* qb = woutb + (size_t)1024 * 1024;          // 64*2048*64
  unsigned short* kb = qb + (size_t)64 * 2048 * 64;
  unsigned short* vb = kb + (size_t)64 * 2048 * 64;
  unsigned short* vtb = xb;
  unsigned short* ob = vb;

  cast3_f32_bf16<<<12288, 256, 0, stream>>>(x, w_qkv, w_out, xb, wqkvb, woutb);
  gemm_qkv<<<dim3(24, 64), 256, 0, stream>>>(xb, wqkvb, qb, kb, vb);
  transpose_v<<<dim3(32, 64), 256, 0, stream>>>(vb, vtb);
  attn_swa<<<2048, 256, 0, stream>>>(qb, kb, vtb, ob);
  gemm_out<<<dim3(8, 64), 256, 0, stream>>>(ob, woutb, out);
}